// Round 7
// baseline (5265.249 us; speedup 1.0000x reference)
//
#include <hip/hip_runtime.h>
#include <hip/hip_bf16.h>

#define N_USERS 100000
#define N_NODES 150000
#define EMB 64
#define RPB 128              // rows per bucket
#define SH 7                 // log2(RPB)
#define NB 1172              // ceil(150000/128)
#define CHUNK 32768
#define CAP 8192             // per-bucket LDS record capacity (mean 5461, 37 sigma)
#define NSEG 8               // column segments (2.4 MB of bf16 table each)
#define SEGW 18752           // ceil(150016/8): seg = col / SEGW in [0,7]
#define NBLK 1024            // spmm grid: 4 blocks/CU on 256 CUs (LDS-bounded, co-resident)
#define RPW 37               // rows per wave: 1024 blk * 4 waves * 37 = 151552 >= 150000
#define RPBLK 148            // rows per block = 4 waves * RPW

typedef __hip_bfloat16 bf16;

static __device__ inline float bf2f(unsigned short u) {
    return __uint_as_float((unsigned)u << 16);
}
static __device__ inline unsigned short f2bf(float f) {
    bf16 h = __float2bfloat16(f);
    return *reinterpret_cast<unsigned short*>(&h);
}

// ---- bucket histogram: LDS-combined then global flush ----
__global__ __launch_bounds__(256)
void bucket_hist(const int* __restrict__ rows, int* __restrict__ bh, int nedges) {
    __shared__ int lh[NB];
    int tid = threadIdx.x;
    for (int i = tid; i < NB; i += 256) lh[i] = 0;
    __syncthreads();
    int stride = gridDim.x * blockDim.x;
    for (int e = blockIdx.x * blockDim.x + tid; e < nedges; e += stride)
        atomicAdd(&lh[rows[e] >> SH], 1);
    __syncthreads();
    for (int b = tid; b < NB; b += 256) {
        int h = lh[b];
        if (h) atomicAdd(&bh[b], h);
    }
}

// ---- single-block exclusive scan of NB bucket counts ----
__global__ __launch_bounds__(1024)
void scan_single(const int* __restrict__ bh, int* __restrict__ base,
                 int* __restrict__ cursor, int nedges) {
    __shared__ int wsum[16];
    __shared__ int carry;
    int tid = threadIdx.x, lane = tid & 63, wid = tid >> 6;
    if (tid == 0) carry = 0;
    __syncthreads();
    for (int t0 = 0; t0 < NB; t0 += 1024) {
        int i = t0 + tid;
        int v = (i < NB) ? bh[i] : 0;
        int s = v;
        #pragma unroll
        for (int d = 1; d < 64; d <<= 1) { int t = __shfl_up(s, d); if (lane >= d) s += t; }
        if (lane == 63) wsum[wid] = s;
        __syncthreads();
        if (wid == 0 && lane < 16) {
            int w = wsum[lane];
            #pragma unroll
            for (int d = 1; d < 16; d <<= 1) { int t = __shfl_up(w, d); if (lane >= d) w += t; }
            wsum[lane] = w;
        }
        __syncthreads();
        int excl = (wid ? wsum[wid - 1] : 0) + (s - v) + carry;
        if (i < NB) { base[i] = excl; cursor[i] = excl; }
        __syncthreads();
        if (tid == 1023) carry += wsum[15];
        __syncthreads();
    }
    if (tid == 0) base[NB] = nedges;
}

// ---- chunked scatter into bucket-grouped records (coalesced runs) ----
// rec entry: x = (row_local << 18) | col, y = bits(val)
__global__ __launch_bounds__(512)
void bucket_scatter(const int* __restrict__ rows, const int* __restrict__ cols,
                    const float* __restrict__ vals, int* __restrict__ cursor,
                    int2* __restrict__ rec, int nedges) {
    __shared__ int lh[NB], gb[NB], lc[NB];
    int tid = threadIdx.x;
    int cs = blockIdx.x * CHUNK;
    int cn = min(CHUNK, nedges - cs);
    for (int i = tid; i < NB; i += 512) { lh[i] = 0; lc[i] = 0; }
    __syncthreads();
    for (int i = tid; i < cn; i += 512)
        atomicAdd(&lh[rows[cs + i] >> SH], 1);
    __syncthreads();
    for (int b = tid; b < NB; b += 512) {
        int h = lh[b];
        if (h) gb[b] = atomicAdd(&cursor[b], h);
    }
    __syncthreads();
    for (int i = tid; i < cn; i += 512) {
        int e = cs + i;
        int r = rows[e];
        int b = r >> SH;
        int p = atomicAdd(&lc[b], 1);
        rec[gb[b] + p] = make_int2(((r & (RPB - 1)) << 18) | cols[e],
                                   __float_as_int(vals[e]));
    }
}

// ---- per-bucket LDS counting sort on key (seg<<7)|row_local:
//      rec (bucket-grouped) -> rec (seg-major, row-sorted, repacked (col,val));
//      emits rss[b*1024 + key] = global start of each (seg,row) bin ----
__global__ __launch_bounds__(512)
void sort_bucket(int2* __restrict__ rec, const int* __restrict__ base,
                 int* __restrict__ rss, int nedges) {
    __shared__ int2 lrec[CAP];                 // 64 KB
    __shared__ int cnt[1024], cur[1024];       // 8 KB
    const int b = blockIdx.x, tid = threadIdx.x;
    const int s = base[b], e = base[b + 1], n = e - s;
    for (int i = tid; i < 1024; i += 512) cnt[i] = 0;
    __syncthreads();
    for (int i = tid; i < n; i += 512) {
        int2 r = rec[s + i];                   // coalesced
        lrec[i] = r;
        unsigned rx = (unsigned)r.x;
        int col = (int)(rx & 0x3FFFF);
        int key = ((col / SEGW) << 7) | (int)(rx >> 18);
        atomicAdd(&cnt[key], 1);
    }
    __syncthreads();
    // exclusive scan of cnt[0..1023] by wave 0 (16 chunks of 64)
    if (tid < 64) {
        int carry = 0;
        for (int ch = 0; ch < 16; ++ch) {
            int idx = (ch << 6) + tid;
            int v = cnt[idx];
            int sc = v;
            #pragma unroll
            for (int d = 1; d < 64; d <<= 1) { int t = __shfl_up(sc, d); if (tid >= d) sc += t; }
            cnt[idx] = sc - v + carry;
            carry += __shfl(sc, 63);
        }
    }
    __syncthreads();
    for (int k = tid; k < 1024; k += 512) {
        int off = cnt[k];
        cur[k] = off;
        rss[(b << 10) + k] = s + off;
    }
    if (b == 0 && tid == 0) rss[NB << 10] = nedges;
    __syncthreads();
    for (int i = tid; i < n; i += 512) {
        int2 r = lrec[i];
        unsigned rx = (unsigned)r.x;
        int col = (int)(rx & 0x3FFFF);
        int key = ((col / SEGW) << 7) | (int)(rx >> 18);
        int pos = atomicAdd(&cur[key], 1);
        rec[s + pos] = make_int2(col, r.y);    // (col, val), same-size in-place
    }
}

// ---- convert f32 (ue|ie) -> contiguous bf16 ego table ----
__global__ __launch_bounds__(256)
void cvt_ego(const float* __restrict__ ue, const float* __restrict__ ie,
             unsigned short* __restrict__ ego) {
    const int total4 = N_NODES * EMB / 4;
    const int userEnd4 = N_USERS * EMB / 4;
    int stride = gridDim.x * blockDim.x;
    for (int i = blockIdx.x * blockDim.x + threadIdx.x; i < total4; i += stride) {
        float4 v = (i < userEnd4) ? ((const float4*)ue)[i]
                                  : ((const float4*)ie)[i - userEnd4];
        ushort4 o;
        o.x = f2bf(v.x); o.y = f2bf(v.y); o.z = f2bf(v.z); o.w = f2bf(v.w);
        ((ushort4*)ego)[i] = o;
    }
}

// ---- best-effort grid barrier: paces phases for L2 locality only.
//      Bounded spin; timeout degrades locality, never correctness. ----
static __device__ inline void phase_barrier(int* arr, int target) {
    __syncthreads();
    if (threadIdx.x == 0) {
        __hip_atomic_fetch_add(arr, 1, __ATOMIC_RELEASE, __HIP_MEMORY_SCOPE_AGENT);
        int lim = 384;
        while (__hip_atomic_load(arr, __ATOMIC_ACQUIRE, __HIP_MEMORY_SCOPE_AGENT) < target
               && --lim > 0)
            __builtin_amdgcn_s_sleep(8);
    }
    __syncthreads();
}

// ---- 8-edge broadcast-gather-fma group (zero-padded lanes: v=0 no-op) ----
static __device__ __forceinline__ float dot_chunk(int rcx, int rcy, int cnt, int lane,
                                                  const unsigned short* __restrict__ x,
                                                  float acc) {
    for (int j = 0; j < cnt; j += 8) {
        int   c0 = __shfl(rcx, j + 0); float v0 = __int_as_float(__shfl(rcy, j + 0));
        int   c1 = __shfl(rcx, j + 1); float v1 = __int_as_float(__shfl(rcy, j + 1));
        int   c2 = __shfl(rcx, j + 2); float v2 = __int_as_float(__shfl(rcy, j + 2));
        int   c3 = __shfl(rcx, j + 3); float v3 = __int_as_float(__shfl(rcy, j + 3));
        int   c4 = __shfl(rcx, j + 4); float v4 = __int_as_float(__shfl(rcy, j + 4));
        int   c5 = __shfl(rcx, j + 5); float v5 = __int_as_float(__shfl(rcy, j + 5));
        int   c6 = __shfl(rcx, j + 6); float v6 = __int_as_float(__shfl(rcy, j + 6));
        int   c7 = __shfl(rcx, j + 7); float v7 = __int_as_float(__shfl(rcy, j + 7));
        float x0 = bf2f(x[(c0 << 6) | lane]);
        float x1 = bf2f(x[(c1 << 6) | lane]);
        float x2 = bf2f(x[(c2 << 6) | lane]);
        float x3 = bf2f(x[(c3 << 6) | lane]);
        float x4 = bf2f(x[(c4 << 6) | lane]);
        float x5 = bf2f(x[(c5 << 6) | lane]);
        float x6 = bf2f(x[(c6 << 6) | lane]);
        float x7 = bf2f(x[(c7 << 6) | lane]);
        acc = fmaf(v0, x0, acc);
        acc = fmaf(v1, x1, acc);
        acc = fmaf(v2, x2, acc);
        acc = fmaf(v3, x3, acc);
        acc = fmaf(v4, x4, acc);
        acc = fmaf(v5, x5, acc);
        acc = fmaf(v6, x6, acc);
        acc = fmaf(v7, x7, acc);
    }
    return acc;
}

// ---- phase-sliced SpMM: persistent blocks, LDS row-accumulator,
//      phase p touches only cols in segment p (2.4 MB, L2-resident) ----
__global__ __launch_bounds__(256, 4)
void spmm_phase(const int2* __restrict__ rec, const int* __restrict__ rss,
                const unsigned short* __restrict__ x, unsigned short* __restrict__ y,
                int* __restrict__ arr) {
    __shared__ float lacc[RPBLK * EMB];        // 37.9 KB -> 4 blocks/CU
    const int tid = threadIdx.x, lane = tid & 63, wloc = tid >> 6;
    const int rbase = blockIdx.x * RPBLK;      // block's first row
    for (int i = tid; i < RPBLK * EMB; i += 256) lacc[i] = 0.f;
    __syncthreads();
    for (int ph = 0; ph < NSEG; ++ph) {
        for (int i = 0; i < RPW; ++i) {
            int rl = wloc * RPW + i;
            int r = rbase + rl;
            if (r < N_NODES) {
                int idx = ((r >> SH) << 10) | (ph << SH) | (r & (RPB - 1));
                int s = rss[idx], e = rss[idx + 1];
                if (s < e) {
                    float a = lacc[(rl << 6) | lane];
                    for (int k0 = s; k0 < e; k0 += 64) {
                        int kk = k0 + lane;
                        int2 rc = make_int2(0, 0);
                        if (kk < e) rc = rec[kk];
                        a = dot_chunk(rc.x, rc.y, min(64, e - k0), lane, x, a);
                    }
                    lacc[(rl << 6) | lane] = a;
                }
            }
        }
        if (ph < NSEG - 1) phase_barrier(arr, (ph + 1) * NBLK);
    }
    __syncthreads();
    for (int i = 0; i < RPW; ++i) {
        int rl = wloc * RPW + i;
        int r = rbase + rl;
        if (r < N_NODES)
            y[(size_t)r * EMB + lane] = f2bf(lacc[(rl << 6) | lane]);
    }
}

// ---- batch-row output kernels ----
__global__ void out_first(const int* __restrict__ user, const int* __restrict__ item,
                          const float* __restrict__ ue, const float* __restrict__ ie,
                          const unsigned short* __restrict__ h1,
                          float* __restrict__ out, int batch) {
    int wave = (blockIdx.x * blockDim.x + threadIdx.x) >> 6;
    int lane = threadIdx.x & 63;
    if (wave >= 2 * batch) return;
    float egov;
    int node;
    if (wave < batch) {
        int u = user[wave];
        node = u;
        egov = ue[(size_t)u * EMB + lane];
    } else {
        int it = item[wave - batch];
        node = N_USERS + it;
        egov = ie[(size_t)it * EMB + lane];
    }
    out[(size_t)wave * EMB + lane] = egov + bf2f(h1[(size_t)node * EMB + lane]);
}

__global__ void out_add(const int* __restrict__ user, const int* __restrict__ item,
                        const unsigned short* __restrict__ h, float* __restrict__ out,
                        int batch, float scale) {
    int wave = (blockIdx.x * blockDim.x + threadIdx.x) >> 6;
    int lane = threadIdx.x & 63;
    if (wave < 2 * batch) {
        int node = (wave < batch) ? user[wave] : (N_USERS + item[wave - batch]);
        size_t o = (size_t)wave * EMB + lane;
        out[o] = (out[o] + bf2f(h[(size_t)node * EMB + lane])) * scale;
    }
}

// ---- driver ----
extern "C" void kernel_launch(void* const* d_in, const int* in_sizes, int n_in,
                              void* d_out, int out_size, void* d_ws, size_t ws_size,
                              hipStream_t stream) {
    const int*   user = (const int*)d_in[0];
    const int*   item = (const int*)d_in[1];
    const int*   rows = (const int*)d_in[2];
    const int*   cols = (const int*)d_in[3];
    const float* vals = (const float*)d_in[4];
    const float* ue   = (const float*)d_in[5];
    const float* ie   = (const float*)d_in[6];
    float*       out  = (float*)d_out;

    const int nedges = in_sizes[2];
    const int batch  = in_sizes[0];

    const size_t hElems = (size_t)N_NODES * EMB;
    char* p = (char*)d_ws;
    int2*           rec    = (int2*)p;            p += (size_t)nedges * sizeof(int2); // 51.2 MB
    int*            bh     = (int*)p;             p += 8192;  // bh[0..NB); arr at bh+1280
    int*            base   = (int*)p;             p += 8192;  // NB+1 ints
    int*            cursor = (int*)p;             p += 8192;
    int*            rss    = (int*)p;             p += (size_t)(NB * 1024 + 16) * 4;  // 4.8 MB
    unsigned short* ego    = (unsigned short*)p;  p += hElems * 2;   // 19.2 MB
    unsigned short* hA     = (unsigned short*)p;  p += hElems * 2;
    unsigned short* hB     = (unsigned short*)p;  p += hElems * 2;
    int*            arr    = bh + 1280;           // 3 phase-barrier counters, zeroed with bh

    // --- CSR build: coarse bucket sort, then per-bucket (seg,row) counting sort ---
    hipMemsetAsync(bh, 0, 8192, stream);          // zeroes bh AND arr[0..2]
    bucket_hist<<<1024, 256, 0, stream>>>(rows, bh, nedges);
    scan_single<<<1, 1024, 0, stream>>>(bh, base, cursor, nedges);
    bucket_scatter<<<(nedges + CHUNK - 1) / CHUNK, 512, 0, stream>>>(
        rows, cols, vals, cursor, rec, nedges);
    sort_bucket<<<NB, 512, 0, stream>>>(rec, base, rss, nedges);

    // --- ego table in bf16 ---
    cvt_ego<<<2048, 256, 0, stream>>>(ue, ie, ego);

    // --- 3 propagation layers (phase-sliced, LDS acc) ---
    const int oblocks = (2 * batch * 64) / 256;

    spmm_phase<<<NBLK, 256, 0, stream>>>(rec, rss, ego, hA, arr + 0);
    out_first<<<oblocks, 256, 0, stream>>>(user, item, ue, ie, hA, out, batch);

    spmm_phase<<<NBLK, 256, 0, stream>>>(rec, rss, hA, hB, arr + 1);
    out_add<<<oblocks, 256, 0, stream>>>(user, item, hB, out, batch, 1.0f);

    spmm_phase<<<NBLK, 256, 0, stream>>>(rec, rss, hB, hA, arr + 2);
    out_add<<<oblocks, 256, 0, stream>>>(user, item, hA, out, batch, 0.25f);
}

// Round 8
// 1810.612 us; speedup vs baseline: 2.9080x; 2.9080x over previous
//
#include <hip/hip_runtime.h>
#include <hip/hip_bf16.h>

#define N_USERS 100000
#define N_NODES 150000
#define EMB 64
#define RPB 128              // rows per bucket
#define SH 7                 // log2(RPB)
#define NB 1172              // ceil(150000/128)
#define CHUNK 32768
#define CAP 8192             // per-bucket LDS record capacity (mean 5461, 37 sigma)
#define NSEG 8               // column segments (2.4 MB of bf16 table each)
#define SEGW 18752           // ceil(150016/8): seg = col / SEGW in [0,7]
#define NBLK 1024            // spmm grid: 4 blocks/CU on 256 CUs (LDS-bounded, co-resident)
#define RPW 37               // rows per wave: 1024 blk * 4 waves * 37 = 151552 >= 150000
#define RPBLK 148            // rows per block = 4 waves * RPW
#define NGRP 8               // barrier groups (assumed XCDs), bid & 7
#define BPG (NBLK / NGRP)    // 128 blocks per group

typedef __hip_bfloat16 bf16;

static __device__ inline float bf2f(unsigned short u) {
    return __uint_as_float((unsigned)u << 16);
}
static __device__ inline unsigned short f2bf(float f) {
    bf16 h = __float2bfloat16(f);
    return *reinterpret_cast<unsigned short*>(&h);
}

// ---- L2-scope (XCD-local) primitives: NO sc1 -> op completes in this XCD's L2.
//      sc0 on the load bypasses L1 so polls observe L2 updates. ----
static __device__ inline void l2_add1(unsigned* p) {
    unsigned one = 1u;
    asm volatile("global_atomic_add %0, %1, off" :: "v"(p), "v"(one) : "memory");
}
static __device__ inline unsigned l2_load(unsigned* p) {
    unsigned v;
    asm volatile("global_load_dword %0, %1, off sc0\n\t"
                 "s_waitcnt vmcnt(0)"
                 : "=v"(v) : "v"(p) : "memory");
    return v;
}

// ---- bucket histogram: LDS-combined then global flush ----
__global__ __launch_bounds__(256)
void bucket_hist(const int* __restrict__ rows, int* __restrict__ bh, int nedges) {
    __shared__ int lh[NB];
    int tid = threadIdx.x;
    for (int i = tid; i < NB; i += 256) lh[i] = 0;
    __syncthreads();
    int stride = gridDim.x * blockDim.x;
    for (int e = blockIdx.x * blockDim.x + tid; e < nedges; e += stride)
        atomicAdd(&lh[rows[e] >> SH], 1);
    __syncthreads();
    for (int b = tid; b < NB; b += 256) {
        int h = lh[b];
        if (h) atomicAdd(&bh[b], h);
    }
}

// ---- single-block exclusive scan of NB bucket counts ----
__global__ __launch_bounds__(1024)
void scan_single(const int* __restrict__ bh, int* __restrict__ base,
                 int* __restrict__ cursor, int nedges) {
    __shared__ int wsum[16];
    __shared__ int carry;
    int tid = threadIdx.x, lane = tid & 63, wid = tid >> 6;
    if (tid == 0) carry = 0;
    __syncthreads();
    for (int t0 = 0; t0 < NB; t0 += 1024) {
        int i = t0 + tid;
        int v = (i < NB) ? bh[i] : 0;
        int s = v;
        #pragma unroll
        for (int d = 1; d < 64; d <<= 1) { int t = __shfl_up(s, d); if (lane >= d) s += t; }
        if (lane == 63) wsum[wid] = s;
        __syncthreads();
        if (wid == 0 && lane < 16) {
            int w = wsum[lane];
            #pragma unroll
            for (int d = 1; d < 16; d <<= 1) { int t = __shfl_up(w, d); if (lane >= d) w += t; }
            wsum[lane] = w;
        }
        __syncthreads();
        int excl = (wid ? wsum[wid - 1] : 0) + (s - v) + carry;
        if (i < NB) { base[i] = excl; cursor[i] = excl; }
        __syncthreads();
        if (tid == 1023) carry += wsum[15];
        __syncthreads();
    }
    if (tid == 0) base[NB] = nedges;
}

// ---- chunked scatter into bucket-grouped records (coalesced runs) ----
// rec entry: x = (row_local << 18) | col, y = bits(val)
__global__ __launch_bounds__(512)
void bucket_scatter(const int* __restrict__ rows, const int* __restrict__ cols,
                    const float* __restrict__ vals, int* __restrict__ cursor,
                    int2* __restrict__ rec, int nedges) {
    __shared__ int lh[NB], gb[NB], lc[NB];
    int tid = threadIdx.x;
    int cs = blockIdx.x * CHUNK;
    int cn = min(CHUNK, nedges - cs);
    for (int i = tid; i < NB; i += 512) { lh[i] = 0; lc[i] = 0; }
    __syncthreads();
    for (int i = tid; i < cn; i += 512)
        atomicAdd(&lh[rows[cs + i] >> SH], 1);
    __syncthreads();
    for (int b = tid; b < NB; b += 512) {
        int h = lh[b];
        if (h) gb[b] = atomicAdd(&cursor[b], h);
    }
    __syncthreads();
    for (int i = tid; i < cn; i += 512) {
        int e = cs + i;
        int r = rows[e];
        int b = r >> SH;
        int p = atomicAdd(&lc[b], 1);
        rec[gb[b] + p] = make_int2(((r & (RPB - 1)) << 18) | cols[e],
                                   __float_as_int(vals[e]));
    }
}

// ---- per-bucket LDS counting sort on key (seg<<7)|row_local:
//      rec (bucket-grouped) -> rec (seg-major, row-sorted, repacked (col,val));
//      emits rss[b*1024 + key] = global start of each (seg,row) bin ----
__global__ __launch_bounds__(512)
void sort_bucket(int2* __restrict__ rec, const int* __restrict__ base,
                 int* __restrict__ rss, int nedges) {
    __shared__ int2 lrec[CAP];                 // 64 KB
    __shared__ int cnt[1024], cur[1024];       // 8 KB
    const int b = blockIdx.x, tid = threadIdx.x;
    const int s = base[b], e = base[b + 1], n = e - s;
    for (int i = tid; i < 1024; i += 512) cnt[i] = 0;
    __syncthreads();
    for (int i = tid; i < n; i += 512) {
        int2 r = rec[s + i];                   // coalesced
        lrec[i] = r;
        unsigned rx = (unsigned)r.x;
        int col = (int)(rx & 0x3FFFF);
        int key = ((col / SEGW) << 7) | (int)(rx >> 18);
        atomicAdd(&cnt[key], 1);
    }
    __syncthreads();
    // exclusive scan of cnt[0..1023] by wave 0 (16 chunks of 64)
    if (tid < 64) {
        int carry = 0;
        for (int ch = 0; ch < 16; ++ch) {
            int idx = (ch << 6) + tid;
            int v = cnt[idx];
            int sc = v;
            #pragma unroll
            for (int d = 1; d < 64; d <<= 1) { int t = __shfl_up(sc, d); if (tid >= d) sc += t; }
            cnt[idx] = sc - v + carry;
            carry += __shfl(sc, 63);
        }
    }
    __syncthreads();
    for (int k = tid; k < 1024; k += 512) {
        int off = cnt[k];
        cur[k] = off;
        rss[(b << 10) + k] = s + off;
    }
    if (b == 0 && tid == 0) rss[NB << 10] = nedges;
    __syncthreads();
    for (int i = tid; i < n; i += 512) {
        int2 r = lrec[i];
        unsigned rx = (unsigned)r.x;
        int col = (int)(rx & 0x3FFFF);
        int key = ((col / SEGW) << 7) | (int)(rx >> 18);
        int pos = atomicAdd(&cur[key], 1);
        rec[s + pos] = make_int2(col, r.y);    // (col, val), same-size in-place
    }
}

// ---- convert f32 (ue|ie) -> contiguous bf16 ego table ----
__global__ __launch_bounds__(256)
void cvt_ego(const float* __restrict__ ue, const float* __restrict__ ie,
             unsigned short* __restrict__ ego) {
    const int total4 = N_NODES * EMB / 4;
    const int userEnd4 = N_USERS * EMB / 4;
    int stride = gridDim.x * blockDim.x;
    for (int i = blockIdx.x * blockDim.x + threadIdx.x; i < total4; i += stride) {
        float4 v = (i < userEnd4) ? ((const float4*)ue)[i]
                                  : ((const float4*)ie)[i - userEnd4];
        ushort4 o;
        o.x = f2bf(v.x); o.y = f2bf(v.y); o.z = f2bf(v.z); o.w = f2bf(v.w);
        ((ushort4*)ego)[i] = o;
    }
}

// ---- 8-edge broadcast-gather-fma group (zero-padded lanes: v=0 no-op) ----
static __device__ __forceinline__ float dot_chunk(int rcx, int rcy, int cnt, int lane,
                                                  const unsigned short* __restrict__ x,
                                                  float acc) {
    for (int j = 0; j < cnt; j += 8) {
        int   c0 = __shfl(rcx, j + 0); float v0 = __int_as_float(__shfl(rcy, j + 0));
        int   c1 = __shfl(rcx, j + 1); float v1 = __int_as_float(__shfl(rcy, j + 1));
        int   c2 = __shfl(rcx, j + 2); float v2 = __int_as_float(__shfl(rcy, j + 2));
        int   c3 = __shfl(rcx, j + 3); float v3 = __int_as_float(__shfl(rcy, j + 3));
        int   c4 = __shfl(rcx, j + 4); float v4 = __int_as_float(__shfl(rcy, j + 4));
        int   c5 = __shfl(rcx, j + 5); float v5 = __int_as_float(__shfl(rcy, j + 5));
        int   c6 = __shfl(rcx, j + 6); float v6 = __int_as_float(__shfl(rcy, j + 6));
        int   c7 = __shfl(rcx, j + 7); float v7 = __int_as_float(__shfl(rcy, j + 7));
        float x0 = bf2f(x[(c0 << 6) | lane]);
        float x1 = bf2f(x[(c1 << 6) | lane]);
        float x2 = bf2f(x[(c2 << 6) | lane]);
        float x3 = bf2f(x[(c3 << 6) | lane]);
        float x4 = bf2f(x[(c4 << 6) | lane]);
        float x5 = bf2f(x[(c5 << 6) | lane]);
        float x6 = bf2f(x[(c6 << 6) | lane]);
        float x7 = bf2f(x[(c7 << 6) | lane]);
        acc = fmaf(v0, x0, acc);
        acc = fmaf(v1, x1, acc);
        acc = fmaf(v2, x2, acc);
        acc = fmaf(v3, x3, acc);
        acc = fmaf(v4, x4, acc);
        acc = fmaf(v5, x5, acc);
        acc = fmaf(v6, x6, acc);
        acc = fmaf(v7, x7, acc);
    }
    return acc;
}

// ---- phase-sliced SpMM: persistent blocks, LDS row-accumulator,
//      per-XCD-group best-effort barrier (L2-scope atomics, bounded spin).
//      Accumulation order is static -> output bit-deterministic regardless
//      of barrier outcome; barrier affects L2 locality (speed) only. ----
__global__ __launch_bounds__(256, 4)
void spmm_phase(const int2* __restrict__ rec, const int* __restrict__ rss,
                const unsigned short* __restrict__ x, unsigned short* __restrict__ y,
                unsigned* __restrict__ xcnt) {
    __shared__ float lacc[RPBLK * EMB];        // 37.9 KB -> 4 blocks/CU
    const int tid = threadIdx.x, lane = tid & 63, wloc = tid >> 6;
    const int rbase = blockIdx.x * RPBLK;      // block's first row
    unsigned* ctr = xcnt + (blockIdx.x & (NGRP - 1)) * 32;  // 128B-spaced per group
    unsigned C0 = 0;
    if (tid == 0) C0 = l2_load(ctr);           // per-call base (wrap/stale safe)
    for (int i = tid; i < RPBLK * EMB; i += 256) lacc[i] = 0.f;
    __syncthreads();
    for (int ph = 0; ph < NSEG; ++ph) {
        for (int i = 0; i < RPW; ++i) {
            int rl = wloc * RPW + i;
            int r = rbase + rl;
            if (r < N_NODES) {
                int idx = ((r >> SH) << 10) | (ph << SH) | (r & (RPB - 1));
                int s = rss[idx], e = rss[idx + 1];
                if (s < e) {
                    float a = lacc[(rl << 6) | lane];
                    for (int k0 = s; k0 < e; k0 += 64) {
                        int kk = k0 + lane;
                        int2 rc = make_int2(0, 0);
                        if (kk < e) rc = rec[kk];
                        a = dot_chunk(rc.x, rc.y, min(64, e - k0), lane, x, a);
                    }
                    lacc[(rl << 6) | lane] = a;
                }
            }
        }
        if (ph < NSEG - 1) {
            // per-group barrier: arrive, then bounded poll on OUR group's line
            __syncthreads();
            if (tid == 0) {
                l2_add1(ctr);
                unsigned target = (unsigned)(BPG * (ph + 1));
                int lim = 48;
                while ((unsigned)(l2_load(ctr) - C0) < target && --lim > 0)
                    __builtin_amdgcn_s_sleep(16);
            }
            __syncthreads();
        }
    }
    __syncthreads();
    for (int i = 0; i < RPW; ++i) {
        int rl = wloc * RPW + i;
        int r = rbase + rl;
        if (r < N_NODES)
            y[(size_t)r * EMB + lane] = f2bf(lacc[(rl << 6) | lane]);
    }
}

// ---- batch-row output kernels ----
__global__ void out_first(const int* __restrict__ user, const int* __restrict__ item,
                          const float* __restrict__ ue, const float* __restrict__ ie,
                          const unsigned short* __restrict__ h1,
                          float* __restrict__ out, int batch) {
    int wave = (blockIdx.x * blockDim.x + threadIdx.x) >> 6;
    int lane = threadIdx.x & 63;
    if (wave >= 2 * batch) return;
    float egov;
    int node;
    if (wave < batch) {
        int u = user[wave];
        node = u;
        egov = ue[(size_t)u * EMB + lane];
    } else {
        int it = item[wave - batch];
        node = N_USERS + it;
        egov = ie[(size_t)it * EMB + lane];
    }
    out[(size_t)wave * EMB + lane] = egov + bf2f(h1[(size_t)node * EMB + lane]);
}

__global__ void out_add(const int* __restrict__ user, const int* __restrict__ item,
                        const unsigned short* __restrict__ h, float* __restrict__ out,
                        int batch, float scale) {
    int wave = (blockIdx.x * blockDim.x + threadIdx.x) >> 6;
    int lane = threadIdx.x & 63;
    if (wave < 2 * batch) {
        int node = (wave < batch) ? user[wave] : (N_USERS + item[wave - batch]);
        size_t o = (size_t)wave * EMB + lane;
        out[o] = (out[o] + bf2f(h[(size_t)node * EMB + lane])) * scale;
    }
}

// ---- driver ----
extern "C" void kernel_launch(void* const* d_in, const int* in_sizes, int n_in,
                              void* d_out, int out_size, void* d_ws, size_t ws_size,
                              hipStream_t stream) {
    const int*   user = (const int*)d_in[0];
    const int*   item = (const int*)d_in[1];
    const int*   rows = (const int*)d_in[2];
    const int*   cols = (const int*)d_in[3];
    const float* vals = (const float*)d_in[4];
    const float* ue   = (const float*)d_in[5];
    const float* ie   = (const float*)d_in[6];
    float*       out  = (float*)d_out;

    const int nedges = in_sizes[2];
    const int batch  = in_sizes[0];

    const size_t hElems = (size_t)N_NODES * EMB;
    char* p = (char*)d_ws;
    int2*           rec    = (int2*)p;            p += (size_t)nedges * sizeof(int2); // 51.2 MB
    int*            bh     = (int*)p;             p += 8192;  // bh[0..NB); xcnt at bh+1280
    int*            base   = (int*)p;             p += 8192;  // NB+1 ints
    int*            cursor = (int*)p;             p += 8192;
    int*            rss    = (int*)p;             p += (size_t)(NB * 1024 + 16) * 4;  // 4.8 MB
    unsigned short* ego    = (unsigned short*)p;  p += hElems * 2;   // 19.2 MB
    unsigned short* hA     = (unsigned short*)p;  p += hElems * 2;
    unsigned short* hB     = (unsigned short*)p;  p += hElems * 2;
    unsigned*       xcnt0  = (unsigned*)(bh + 1280);   // 3 layer-counter arrays,
    unsigned*       xcnt1  = xcnt0 + NGRP * 32;        // 8 groups x 128B each,
    unsigned*       xcnt2  = xcnt1 + NGRP * 32;        // zeroed with bh (8 KB memset)

    // --- CSR build: coarse bucket sort, then per-bucket (seg,row) counting sort ---
    hipMemsetAsync(bh, 0, 8192, stream);          // zeroes bh AND xcnt0/1/2
    bucket_hist<<<1024, 256, 0, stream>>>(rows, bh, nedges);
    scan_single<<<1, 1024, 0, stream>>>(bh, base, cursor, nedges);
    bucket_scatter<<<(nedges + CHUNK - 1) / CHUNK, 512, 0, stream>>>(
        rows, cols, vals, cursor, rec, nedges);
    sort_bucket<<<NB, 512, 0, stream>>>(rec, base, rss, nedges);

    // --- ego table in bf16 ---
    cvt_ego<<<2048, 256, 0, stream>>>(ue, ie, ego);

    // --- 3 propagation layers (phase-sliced, LDS acc, per-XCD barriers) ---
    const int oblocks = (2 * batch * 64) / 256;

    spmm_phase<<<NBLK, 256, 0, stream>>>(rec, rss, ego, hA, xcnt0);
    out_first<<<oblocks, 256, 0, stream>>>(user, item, ue, ie, hA, out, batch);

    spmm_phase<<<NBLK, 256, 0, stream>>>(rec, rss, hA, hB, xcnt1);
    out_add<<<oblocks, 256, 0, stream>>>(user, item, hB, out, batch, 1.0f);

    spmm_phase<<<NBLK, 256, 0, stream>>>(rec, rss, hB, hA, xcnt2);
    out_add<<<oblocks, 256, 0, stream>>>(user, item, hA, out, batch, 0.25f);
}